// Round 5
// baseline (5052.759 us; speedup 1.0000x reference)
//
#include <hip/hip_runtime.h>
#include <stdint.h>

#define V 4096
#define D 128
#define E 12288
#define NPAD 16384
#define HALF 8192
#define TARGET 2048
#define MAXM (V - TARGET)    // 2048 max merges
#define ROWU32 256           // 4096 fields * 2 bits = 256 u32 per row (1 KB)
#define CAP 32               // candidates decided per round

// s_waitcnt imms (gfx9): bits 3:0 vmcnt lo, 6:4 expcnt, 11:8 lgkmcnt, 15:14 vmcnt hi
#define WAIT_VM0   0x0F70    // vmcnt(0) only

// ws layout (bytes)
#define WS_N      0u                            // V*ROWU32*4 = 4 MB (2-bit matrix)
#define WS_PRI    (V * ROWU32 * 4u)             // V float
#define WS_KEYS   (WS_PRI + V * 4u)             // NPAD u64
#define WS_PK     (WS_KEYS + NPAD * 8u)         // E u32 (sorted packed edges)
#define WS_PAIRS  (WS_PK + E * 4u)              // MAXM u32
#define WS_MCOUNT (WS_PAIRS + MAXM * 4u)        // 1 int
#define WS_ALIVE  (WS_MCOUNT + 16u)             // V u8

typedef const __attribute__((address_space(1))) unsigned* gas1_t;
typedef __attribute__((address_space(3))) unsigned* las3_t;

__device__ __forceinline__ unsigned getf(const uint4& r, int c) {
    unsigned lo = (c & 2) ? r.z : r.x;
    unsigned hi = (c & 2) ? r.w : r.y;
    return (c & 1) ? hi : lo;
}
__device__ __forceinline__ void andf(uint4& r, int c, unsigned msk) {
    if (c == 0) r.x &= msk; else if (c == 1) r.y &= msk;
    else if (c == 2) r.z &= msk; else r.w &= msk;
}
__device__ __forceinline__ void orf(uint4& r, int c, unsigned v) {
    if (c == 0) r.x |= v; else if (c == 1) r.y |= v;
    else if (c == 2) r.z |= v; else r.w |= v;
}

__global__ void k_scatter(const int* __restrict__ edges, unsigned* __restrict__ n32) {
    int e = blockIdx.x * 256 + threadIdx.x;
    if (e < E) {
        int a = edges[e], b = edges[E + e];
        atomicOr(&n32[a * ROWU32 + (b >> 4)], 2u << ((b & 15) * 2));
        atomicOr(&n32[b * ROWU32 + (a >> 4)], 2u << ((a & 15) * 2));
    }
}

// numpy pairwise f32 sum for n=128 (matches np oracle reduction order)
__global__ void k_pri(const float* __restrict__ f, float* __restrict__ pri) {
    int v = blockIdx.x * 256 + threadIdx.x;
    if (v < V) {
        const float* p = f + v * D;
        float r[8];
#pragma unroll
        for (int j = 0; j < 8; j++) r[j] = __fmul_rn(p[j], p[j]);
        for (int i = 8; i < D; i += 8) {
#pragma unroll
            for (int j = 0; j < 8; j++)
                r[j] = __fadd_rn(r[j], __fmul_rn(p[i + j], p[i + j]));
        }
        float s01 = __fadd_rn(r[0], r[1]);
        float s23 = __fadd_rn(r[2], r[3]);
        float s45 = __fadd_rn(r[4], r[5]);
        float s67 = __fadd_rn(r[6], r[7]);
        pri[v] = __fadd_rn(__fadd_rn(s01, s23), __fadd_rn(s45, s67));
    }
}

__global__ void k_keys(const int* __restrict__ edges, const float* __restrict__ pri,
                       unsigned long long* __restrict__ keys) {
    int s = blockIdx.x * 256 + threadIdx.x;
    if (s < NPAD) {
        unsigned long long rec;
        if (s < E) {
            int a = edges[s], b = edges[E + s];
            float k = __fadd_rn(pri[a], pri[b]);   // epri >= 0 -> bits monotone
            rec = ((unsigned long long)__float_as_uint(k) << 32) | (unsigned)s;
        } else {
            rec = (0xFFFFFFFFull << 32) | (unsigned)s;
        }
        keys[s] = rec;
    }
}

// bitonic sort one 8192-element half in LDS; 2 blocks run concurrently
__launch_bounds__(1024)
__global__ void k_sort2(unsigned long long* __restrict__ keys) {
    __shared__ unsigned long long srt[HALF];
    const int tid = threadIdx.x;
    unsigned long long* base = keys + blockIdx.x * HALF;
    for (int s = tid; s < HALF; s += 1024) srt[s] = base[s];
    __syncthreads();
    for (int k = 2; k <= HALF; k <<= 1) {
        for (int j = k >> 1; j >= 1; j >>= 1) {
            for (int i = tid; i < HALF; i += 1024) {
                int ixj = i ^ j;
                if (ixj > i) {
                    unsigned long long x = srt[i], y = srt[ixj];
                    bool up = ((i & k) == 0);
                    if ((x > y) == up) { srt[i] = y; srt[ixj] = x; }
                }
            }
            __syncthreads();
        }
    }
    for (int s = tid; s < HALF; s += 1024) base[s] = srt[s];
}

// merge-path the two sorted halves; emit packed (v0<<16|v1) in global order
__launch_bounds__(64)
__global__ void k_mergepath(const unsigned long long* __restrict__ keys,
                            const int* __restrict__ edges, unsigned* __restrict__ pkG) {
    int t = blockIdx.x * 64 + threadIdx.x;
    if (t >= E / 64) return;
    const unsigned long long* A = keys;
    const unsigned long long* B = keys + HALF;
    int d = t * 64;
    int lo = d > HALF ? d - HALF : 0;
    int hi = d < HALF ? d : HALF;
    while (lo < hi) {
        int mid = (lo + hi) >> 1;
        if (A[mid] < B[d - 1 - mid]) lo = mid + 1; else hi = mid;
    }
    int ia = lo, ib = d - lo;
    for (int o = d; o < d + 64; o++) {
        bool takeA = (ib >= HALF) || (ia < HALF && A[ia] < B[ib]);
        unsigned long long r = takeA ? A[ia++] : B[ib++];
        int e = (int)(r & 0xFFFFFFFFull);
        int a = edges[e], b = edges[E + e];
        pkG[o] = ((unsigned)a << 16) | (unsigned)b;
    }
}

// ONE wave: candidate pool + EXACT endpoint-rule selection + PARALLEL apply.
// Selection (pure VALU, priority order): killed-by-kept -> dead(final);
// shares-v0-with-kept or any-share-with-earlier-deferred -> defer (exact,
// delayed); else KEPT. Kept set == oracle accepts, pairwise endpoint-disjoint.
// Application: interactions among kept merges live entirely in the 2m x 2m
// submatrix over kept endpoints -> sequential register machine (shfl+VALU,
// no barriers) computes exact values there; rows applied in parallel with
// machine values patched into kept-v0 columns; S0-based fixups (exact for
// generic rows) skip kept-v0 rows. Only kept rows are fetched (post-select).
__launch_bounds__(64, 1)
__global__ void k_collapse(const unsigned* __restrict__ pkG, unsigned* n32,
                           unsigned* __restrict__ pairsG, int* __restrict__ mcountG,
                           uint8_t* __restrict__ aliveG, float* __restrict__ out) {
    __shared__ unsigned shRows[2 * CAP * ROWU32];   // 64 KB: rank r -> slots 2r,2r+1
    __shared__ uint8_t  alive[V];                   // 4 KB
    __shared__ uint8_t  keptMark[V];                // 4 KB: kept v0 this round
    __shared__ unsigned shCand[CAP];
    __shared__ unsigned shEp[2 * CAP];              // kept endpoint ids
    __shared__ unsigned shM[64 * 4];                // machine result rows (1 KB)
    const int lane = threadIdx.x;
    for (int v = lane; v < V; v += 64) { alive[v] = 1; keptMark[v] = 0; }
    __syncthreads();

    int cnt = V, mcount = 0, head = 64;
    unsigned pkv = pkG[lane];                       // pool: one candidate per lane
    bool dec = false;

    while (true) {
        const int a = (int)(pkv >> 16), b = (int)(pkv & 0xFFFFu);
        if (!dec && !(alive[a] && alive[b])) dec = true;
        __builtin_amdgcn_s_waitcnt(WAIT_VM0);        // prior round's stores visible
        if (!dec) {
            unsigned wv = *(volatile unsigned*)(n32 + a * ROWU32 + (b >> 4));
            if (((wv >> ((b & 15) * 2)) & 3u) != 2u) dec = true;  // {2,3} while alive
        }
        unsigned long long mF = __ballot(!dec);

        if (mF) {
            int flagged = (int)__popcll(mF);
            int nacc = flagged < CAP ? flagged : CAP;
            const int limit = cnt - TARGET;          // >= 1 here
            int myK = -1;
            if (!dec) {
                int rank = (int)__popcll(mF & ((1ull << lane) - 1ull));
                if (rank < CAP) { myK = rank; shCand[rank] = pkv; }
            }
            __syncthreads();

            // ---- endpoint-equality masks (register/shfl; bits j<k only) ----
            unsigned cpk = (lane < nacc) ? shCand[lane] : 0u;
            const int v0k = (int)(cpk >> 16), v1k = (int)(cpk & 0xFFFFu);
            unsigned killM = 0u, v0sM = 0u, anyM = 0u;
            for (int j = 0; j < nacc; j++) {
                unsigned cpj = (unsigned)__shfl((int)cpk, j);
                int v0j = (int)(cpj >> 16), v1j = (int)(cpj & 0xFFFFu);
                if (j < lane && lane < nacc) {
                    bool kill = (v1j == v0k) || (v1j == v1k);
                    bool v0s  = (v0j == v0k) || (v0j == v1k);
                    if (kill) killM |= 1u << j;
                    if (v0s)  v0sM  |= 1u << j;
                    if (kill || v0s) anyM |= 1u << j;
                }
            }
            // ---- exact sequential selection (replicated, pure VALU) ----
            unsigned kept = 0u, deferm = 0u, deadm = 0u;
            int m = 0; bool limitHit = false;
            for (int k = 0; k < nacc; k++) {
                unsigned Km = (unsigned)__shfl((int)killM, k);
                unsigned Vm = (unsigned)__shfl((int)v0sM, k);
                unsigned Am = (unsigned)__shfl((int)anyM, k);
                unsigned bit = 1u << k;
                if (limitHit)                        { deadm |= bit; continue; }
                if (Km & kept)                       { deadm |= bit; continue; }
                if ((Vm & kept) | (Am & deferm))     { deferm |= bit; continue; }
                kept |= bit; m++;
                if (m == limit) limitHit = true;
            }
            if (myK >= 0 && (((kept | deadm) >> myK) & 1u)) dec = true;

            // ---- MARK: alive, merge log (priority order), kept lists ----
            if (lane < nacc && ((kept >> lane) & 1u)) {
                int r = __popc(kept & ((1u << lane) - 1u));
                shEp[2 * r] = (unsigned)v0k;
                shEp[2 * r + 1] = (unsigned)v1k;
                alive[v1k] = 0;
                keptMark[v0k] = 1;
                pairsG[mcount + r] = cpk;
            }
            mcount += m; cnt -= m;
            __syncthreads();
            if (cnt == TARGET) break;                // matrix state no longer needed

            // ---- FETCH only kept rows: rank r -> slots 2r (v0), 2r+1 (v1) ----
            for (int r = 0; r < m; r++) {
                int v0 = (int)shEp[2 * r], v1 = (int)shEp[2 * r + 1];
                __builtin_amdgcn_global_load_lds(
                    (gas1_t)(n32 + v0 * ROWU32 + lane * 4),
                    (las3_t)(shRows + (2 * r) * ROWU32), 16, 0, 0);
                __builtin_amdgcn_global_load_lds(
                    (gas1_t)(n32 + v1 * ROWU32 + lane * 4),
                    (las3_t)(shRows + (2 * r + 1) * ROWU32), 16, 0, 0);
            }
            __builtin_amdgcn_s_waitcnt(WAIT_VM0);
            __syncthreads();

            // ---- MACHINE: exact sequential emulation on 2m x 2m submatrix.
            // Lane x (< 2m) holds row x as 64 2-bit fields in M0..M3.
            const int twom = 2 * m;
            unsigned M0 = 0u, M1 = 0u, M2 = 0u, M3 = 0u;
            for (int y = 0; y < twom; y++) {
                int epy = (int)shEp[y];
                if (lane < twom) {
                    unsigned wv = shRows[lane * ROWU32 + (epy >> 4)];
                    unsigned f = (wv >> ((epy & 15) * 2)) & 3u;
                    unsigned sh = (unsigned)((y & 15) * 2);
                    if (y < 16) M0 |= f << sh;
                    else if (y < 32) M1 |= f << sh;
                    else if (y < 48) M2 |= f << sh;
                    else M3 |= f << sh;
                }
            }
            for (int r = 0; r < m; r++) {
                const int i0 = 2 * r, i1 = 2 * r + 1;   // same 16-field word (i0 even)
                unsigned r0 = (unsigned)__shfl((int)M0, i1);
                unsigned r1 = (unsigned)__shfl((int)M1, i1);
                unsigned r2 = (unsigned)__shfl((int)M2, i1);
                unsigned r3 = (unsigned)__shfl((int)M3, i1);
                const unsigned shA = (unsigned)((i0 & 15) * 2);
                const unsigned shB = (unsigned)((i1 & 15) * 2);
                if (lane == i0) {                    // row i0 += row i1 (sat)
                    M0 = M0 | r0 | ((M0 & r0 & 0xAAAAAAAAu) >> 1);
                    M1 = M1 | r1 | ((M1 & r1 & 0xAAAAAAAAu) >> 1);
                    M2 = M2 | r2 | ((M2 & r2 & 0xAAAAAAAAu) >> 1);
                    M3 = M3 | r3 | ((M3 & r3 & 0xAAAAAAAAu) >> 1);
                    unsigned wz = (i0 < 16) ? M0 : (i0 < 32) ? M1 : (i0 < 48) ? M2 : M3;
                    wz &= ~((3u << shA) | (3u << shB));   // r[v0]=r[v1]=0
                    if (i0 < 16) M0 = wz; else if (i0 < 32) M1 = wz;
                    else if (i0 < 48) M2 = wz; else M3 = wz;
                }
                // col op (all lanes; lane i0 post-row-op -> diag stays 0)
                unsigned w = (i0 < 16) ? M0 : (i0 < 32) ? M1 : (i0 < 48) ? M2 : M3;
                unsigned f0 = (w >> shA) & 3u, f1 = (w >> shB) & 3u;
                unsigned nf = f0 | f1 | ((f0 & f1 & 2u) >> 1);
                w = (w & ~((3u << shA) | (3u << shB))) | (nf << shA);
                if (i0 < 16) M0 = w; else if (i0 < 32) M1 = w;
                else if (i0 < 48) M2 = w; else M3 = w;
                if (lane == i1) { M0 = 0u; M1 = 0u; M2 = 0u; M3 = 0u; }  // row v1 dies
            }
            if (lane < twom) {
                shM[lane * 4 + 0] = M0; shM[lane * 4 + 1] = M1;
                shM[lane * 4 + 2] = M2; shM[lane * 4 + 3] = M3;
            }
            // which kept-v0 columns fall in my 64-field window?
            unsigned jmask = 0u;
            for (int j = 0; j < m; j++)
                if ((int)(shEp[2 * j] >> 6) == lane) jmask |= 1u << j;
            __syncthreads();

            // ---- APPLY: parallel unions + machine-patched kept-v0 cols + fixups ----
            for (int g = 0; g < m; g++) {
                int v0 = (int)shEp[2 * g], v1 = (int)shEp[2 * g + 1];
                uint4 ra = ((const uint4*)(shRows + (2 * g) * ROWU32))[lane];
                uint4 rb = ((const uint4*)(shRows + (2 * g + 1) * ROWU32))[lane];
                uint4 rr;
                rr.x = ra.x | rb.x | ((ra.x & rb.x & 0xAAAAAAAAu) >> 1);
                rr.y = ra.y | rb.y | ((ra.y & rb.y & 0xAAAAAAAAu) >> 1);
                rr.z = ra.z | rb.z | ((ra.z & rb.z & 0xAAAAAAAAu) >> 1);
                rr.w = ra.w | rb.w | ((ra.w & rb.w & 0xAAAAAAAAu) >> 1);
                if ((v0 >> 6) == lane) andf(rr, (v0 >> 4) & 3, ~(3u << ((v0 & 15) * 2)));
                if ((v1 >> 6) == lane) andf(rr, (v1 >> 4) & 3, ~(3u << ((v1 & 15) * 2)));
                unsigned tt = jmask;                 // patch machine columns I own
                while (tt) {
                    int j = __ffs(tt) - 1; tt &= tt - 1u;
                    int v0j = (int)shEp[2 * j];
                    unsigned val = (shM[(2 * g) * 4 + ((2 * j) >> 4)]
                                    >> (((2 * j) & 15) * 2)) & 3u;
                    int c = (v0j >> 4) & 3;
                    unsigned sh = (unsigned)((v0j & 15) * 2);
                    andf(rr, c, ~(3u << sh));
                    orf(rr, c, val << sh);
                }
                ((uint4*)(n32 + v0 * ROWU32))[lane] = rr;
                // fixups (S0-exact for generic rows); skip kept-v0 rows (machine)
                const int wi0 = v0 >> 4;
                const unsigned sh0 = (unsigned)((v0 & 15) * 2);
#pragma unroll
                for (int c2 = 0; c2 < 4; c2++) {
                    unsigned bb = getf(rb, c2);
                    if (!bb) continue;
                    unsigned aa = getf(ra, c2);
                    int xbase = (lane << 6) + (c2 << 4);
                    unsigned t2 = bb;
                    while (t2) {
                        int q = (__ffs(t2) - 1) >> 1;
                        t2 &= ~(3u << (q * 2));
                        int x = xbase + q;
                        if (x != v0 && x != v1 && !keptMark[x]) {
                            unsigned a2 = (aa >> (q * 2)) & 3u;
                            unsigned b2 = (bb >> (q * 2)) & 3u;
                            unsigned n2 = a2 | b2 | ((a2 & b2 & 2u) >> 1);
                            unsigned dx = a2 ^ n2;
                            if (dx) atomicXor(n32 + x * ROWU32 + wi0, dx << sh0);
                        }
                    }
                }
            }
            __syncthreads();
            if (lane < nacc && ((kept >> lane) & 1u)) keptMark[v0k] = 0;
            __syncthreads();
        } else {
            if (head >= E) break;                    // pool empty, stream done
        }

        // ---- COMPACT undecided to low lanes (order-preserving) + REFILL ----
        {
            unsigned long long mU = __ballot(!dec);
            int nU = (int)__popcll(mU);
            int p = 0;
#pragma unroll
            for (int step = 32; step; step >>= 1) {
                int c2 = p + step;
                unsigned long long pref =
                    (c2 >= 64) ? ~0ull : ((1ull << c2) - 1ull);
                if ((int)__popcll(mU & pref) <= lane) p = c2;
            }
            unsigned npkv = (unsigned)__shfl((int)pkv, p);
            if (lane < nU) { pkv = npkv; dec = false; }
            else {
                int idx = head + lane - nU;
                if (idx < E) { pkv = pkG[idx]; dec = false; }
                else dec = true;                     // inactive forever
            }
            head += 64 - nU;
        }
    }

    for (int v = lane; v < V; v += 64) {
        uint8_t ao = alive[v];
        aliveG[v] = ao;
        out[V * D + v] = ao ? 1.0f : 0.0f;
    }
    if (lane == 0) { mcountG[0] = mcount; out[V * D + V] = (float)cnt; }
}

// Replay merge forest: per-vertex (root, weight) then scatter-add w*f[v] into out[root].
__launch_bounds__(256)
__global__ void k_apply(const float* __restrict__ f, const unsigned* __restrict__ pairsG,
                        const int* __restrict__ mcountG, float* __restrict__ out) {
    __shared__ unsigned pl[MAXM];
    __shared__ int rootL[256];
    __shared__ float wL[256];
    const int tid = threadIdx.x;
    const int mc = mcountG[0];
    for (int j = tid; j < mc; j += 256) pl[j] = pairsG[j];
    __syncthreads();
    int cur = blockIdx.x * 256 + tid;
    float w = 1.0f;
    for (int j = 0; j < mc; j++) {
        unsigned p = pl[j];
        int v0 = (int)(p >> 16), v1 = (int)(p & 0xFFFFu);
        if (cur == v1) { cur = v0; w *= 0.5f; }
        else if (cur == v0) w *= 0.5f;
    }
    rootL[tid] = cur;
    wL[tid] = w;
    __syncthreads();
    const int sub = tid >> 7;
    const int d = tid & 127;
    for (int s = 0; s < 256; s += 2) {
        int idx = s + sub;
        int vv = blockIdx.x * 256 + idx;
        atomicAdd(&out[rootL[idx] * D + d], wL[idx] * f[vv * D + d]);
    }
}

extern "C" void kernel_launch(void* const* d_in, const int* in_sizes, int n_in,
                              void* d_out, int out_size, void* d_ws, size_t ws_size,
                              hipStream_t stream) {
    (void)in_sizes; (void)n_in; (void)out_size; (void)ws_size;
    const float* features = (const float*)d_in[0];
    const int* edges = (const int*)d_in[1];
    uint8_t* ws = (uint8_t*)d_ws;
    unsigned* n32 = (unsigned*)(ws + WS_N);
    float* pri = (float*)(ws + WS_PRI);
    unsigned long long* keys = (unsigned long long*)(ws + WS_KEYS);
    unsigned* pkG = (unsigned*)(ws + WS_PK);
    unsigned* pairsG = (unsigned*)(ws + WS_PAIRS);
    int* mcountG = (int*)(ws + WS_MCOUNT);
    uint8_t* aliveG = ws + WS_ALIVE;
    float* out = (float*)d_out;

    hipMemsetAsync(n32, 0, (size_t)V * ROWU32 * 4, stream);
    hipMemsetAsync(out, 0, (size_t)V * D * sizeof(float), stream);
    k_pri<<<(V + 255) / 256, 256, 0, stream>>>(features, pri);
    k_scatter<<<(E + 255) / 256, 256, 0, stream>>>(edges, n32);
    k_keys<<<(NPAD + 255) / 256, 256, 0, stream>>>(edges, pri, keys);
    k_sort2<<<2, 1024, 0, stream>>>(keys);
    k_mergepath<<<(E / 64 + 63) / 64, 64, 0, stream>>>(keys, edges, pkG);
    k_collapse<<<1, 64, 0, stream>>>(pkG, n32, pairsG, mcountG, aliveG, out);
    k_apply<<<V / 256, 256, 0, stream>>>(features, pairsG, mcountG, out);
}